// Round 1
// baseline (618.637 us; speedup 1.0000x reference)
//
#include <hip/hip_runtime.h>

typedef unsigned short u16;
typedef unsigned int u32;
typedef __attribute__((ext_vector_type(8))) short bf16x8;
typedef __attribute__((ext_vector_type(4))) float f32x4;
struct __align__(8) us4 { u16 x, y, z, w; };

#define S_LEN 2048
#define HID   4096
#define NH    32
#define KVH   8
#define HD    128

__device__ inline u16 f2bf(float f) {
  u32 u = __float_as_uint(f);
  u32 r = (u + 0x7fffu + ((u >> 16) & 1u)) >> 16;  // RNE
  return (u16)r;
}
__device__ inline float bf2f(u16 h) { return __uint_as_float(((u32)h) << 16); }

__device__ inline void gld_lds16(const void* g, void* l) {
  __builtin_amdgcn_global_load_lds(
      (const __attribute__((address_space(1))) u32*)g,
      (__attribute__((address_space(3))) u32*)l, 16, 0, 0);
}

// ---------------- fp32 -> bf16 conversion (4 elems/thread, exact grid) ------
__global__ __launch_bounds__(256) void cvt_bf16(const float* __restrict__ in,
                                                u16* __restrict__ out) {
  size_t i = ((size_t)blockIdx.x * 256 + threadIdx.x) * 4;
  f32x4 v = *(const f32x4*)(in + i);
  us4 o;
  o.x = f2bf(v[0]); o.y = f2bf(v[1]); o.z = f2bf(v[2]); o.w = f2bf(v[3]);
  *(us4*)(out + i) = o;
}

// ---------------- NT GEMM core: C(128x128) = A(MxK) * W(NxK)^T --------------
// m97 structure: BK=32, global_load_lds w16, 4 waves in 2x2, 4x4 16x16x32 MFMA
__device__ inline void gemm_core_128(const u16* __restrict__ A,
                                     const u16* __restrict__ W,
                                     int m0, int n0, int K,
                                     u16* lA, u16* lB, f32x4 (&acc)[4][4]) {
  const int t = threadIdx.x;
  const int l = t & 63, w = t >> 6;
  const int quad = l >> 4, l15 = l & 15;
  const int wr = w >> 1, wc = w & 1;
  const int srow = t >> 2;          // 0..63
  const int scol = (t & 3) * 8;     // 0,8,16,24
#pragma unroll
  for (int i = 0; i < 4; i++)
#pragma unroll
    for (int j = 0; j < 4; j++) acc[i][j] = (f32x4){0.f, 0.f, 0.f, 0.f};

  for (int k0 = 0; k0 < K; k0 += 32) {
    // LDS dest offsets are linear in t (= wave base + lane*16B) as required.
    gld_lds16(A + (size_t)(m0 + srow) * K + k0 + scol, lA + srow * 32 + scol);
    gld_lds16(A + (size_t)(m0 + 64 + srow) * K + k0 + scol, lA + (64 + srow) * 32 + scol);
    gld_lds16(W + (size_t)(n0 + srow) * K + k0 + scol, lB + srow * 32 + scol);
    gld_lds16(W + (size_t)(n0 + 64 + srow) * K + k0 + scol, lB + (64 + srow) * 32 + scol);
    __syncthreads();
    bf16x8 af[4], bfr[4];
#pragma unroll
    for (int i = 0; i < 4; i++)
      af[i] = *(const bf16x8*)(lA + (wr * 64 + i * 16 + l15) * 32 + quad * 8);
#pragma unroll
    for (int j = 0; j < 4; j++)
      bfr[j] = *(const bf16x8*)(lB + (wc * 64 + j * 16 + l15) * 32 + quad * 8);
#pragma unroll
    for (int i = 0; i < 4; i++)
#pragma unroll
      for (int j = 0; j < 4; j++)
        acc[i][j] = __builtin_amdgcn_mfma_f32_16x16x32_bf16(af[i], bfr[j], acc[i][j], 0, 0, 0);
    __syncthreads();
  }
}

// ---------------- fused QKV projection ------------------------------------
// grid.x: 0..31 -> Q (bf16 row-major), 32..39 -> K (bf16 row-major),
//         40..47 -> V (bf16 TRANSPOSED: vt[(kvh*128+d)*S + s])
__global__ __launch_bounds__(256)
void gemm_qkv(const u16* __restrict__ xb, const u16* __restrict__ wqb,
              const u16* __restrict__ wkb, const u16* __restrict__ wvb,
              u16* __restrict__ Qp, u16* __restrict__ Kp, u16* __restrict__ vt) {
  __shared__ __align__(16) u16 lA[128 * 32];
  __shared__ __align__(16) u16 lB[128 * 32];
  const int bx = blockIdx.x;
  const int m0 = blockIdx.y * 128;
  const u16* W; u16* C; int n0, ldc, epi;
  if (bx < 32)      { W = wqb; C = Qp; n0 = bx * 128;        ldc = HID;  epi = 0; }
  else if (bx < 40) { W = wkb; C = Kp; n0 = (bx - 32) * 128; ldc = 1024; epi = 0; }
  else              { W = wvb; C = vt; n0 = (bx - 40) * 128; ldc = 0;    epi = 1; }

  f32x4 acc[4][4];
  gemm_core_128(xb, W, m0, n0, HID, lA, lB, acc);

  const int t = threadIdx.x, l = t & 63, w = t >> 6;
  const int quad = l >> 4, l15 = l & 15;
  const int wr = w >> 1, wc = w & 1;
  if (epi == 0) {
#pragma unroll
    for (int i = 0; i < 4; i++) {
      int row0 = m0 + wr * 64 + i * 16 + quad * 4;
#pragma unroll
      for (int j = 0; j < 4; j++) {
        int col = n0 + wc * 64 + j * 16 + l15;
#pragma unroll
        for (int r = 0; r < 4; r++)
          C[(size_t)(row0 + r) * ldc + col] = f2bf(acc[i][j][r]);
      }
    }
  } else {
#pragma unroll
    for (int i = 0; i < 4; i++) {
      int row0 = m0 + wr * 64 + i * 16 + quad * 4;
#pragma unroll
      for (int j = 0; j < 4; j++) {
        int col = n0 + wc * 64 + j * 16 + l15;
        us4 v;
        v.x = f2bf(acc[i][j][0]); v.y = f2bf(acc[i][j][1]);
        v.z = f2bf(acc[i][j][2]); v.w = f2bf(acc[i][j][3]);
        *(us4*)(C + (size_t)col * S_LEN + row0) = v;  // transposed store
      }
    }
  }
}

// ---------------- output projection: d_out(f32) = ab * wo^T -----------------
__global__ __launch_bounds__(256)
void gemm_out(const u16* __restrict__ ab, const u16* __restrict__ wob,
              float* __restrict__ outp) {
  __shared__ __align__(16) u16 lA[128 * 32];
  __shared__ __align__(16) u16 lB[128 * 32];
  const int m0 = blockIdx.y * 128, n0 = blockIdx.x * 128;
  f32x4 acc[4][4];
  gemm_core_128(ab, wob, m0, n0, HID, lA, lB, acc);
  const int t = threadIdx.x, l = t & 63, w = t >> 6;
  const int quad = l >> 4, l15 = l & 15;
  const int wr = w >> 1, wc = w & 1;
#pragma unroll
  for (int i = 0; i < 4; i++) {
    int row0 = m0 + wr * 64 + i * 16 + quad * 4;
#pragma unroll
    for (int j = 0; j < 4; j++) {
      int col = n0 + wc * 64 + j * 16 + l15;
#pragma unroll
      for (int r = 0; r < 4; r++)
        outp[(size_t)(row0 + r) * HID + col] = acc[i][j][r];
    }
  }
}

// ---------------- RMSNorm + RoPE + per-head relayout ------------------------
// one wave per (s, head); lane l handles dims l and l+64 (the RoPE pair)
template <int NHEADS>
__global__ __launch_bounds__(256)
void rope_norm(const u16* __restrict__ Xp, const float* __restrict__ nw,
               const float* __restrict__ cosT, const float* __restrict__ sinT,
               const int* __restrict__ pos, u16* __restrict__ outb) {
  const int t = threadIdx.x, w = t >> 6, l = t & 63;
  const int p = blockIdx.x * 4 + w;
  const int s = p / NHEADS, h = p % NHEADS;
  const u16* xr = Xp + (size_t)s * (NHEADS * HD) + h * HD;
  float x1 = bf2f(xr[l]), x2 = bf2f(xr[l + 64]);
  float ss = x1 * x1 + x2 * x2;
#pragma unroll
  for (int m = 1; m < 64; m <<= 1) ss += __shfl_xor(ss, m);
  float rinv = rsqrtf(ss * (1.0f / 128.0f) + 1e-6f);
  float n1 = x1 * rinv * nw[l];
  float n2 = x2 * rinv * nw[l + 64];
  int ps = pos[s];
  float c1 = cosT[ps * HD + l], s1 = sinT[ps * HD + l];
  float c2 = cosT[ps * HD + l + 64], s2 = sinT[ps * HD + l + 64];
  float y1 = n1 * c1 - n2 * s1;       // d < 64: rotated = -x[d+64]
  float y2 = n2 * c2 + n1 * s2;       // d >= 64: rotated = +x[d-64]
  u16* orow = outb + ((size_t)h * S_LEN + s) * HD;
  orow[l] = f2bf(y1);
  orow[l + 64] = f2bf(y2);
}

// ---------------- causal GQA flash attention --------------------------------
// block = (head, 64 q-rows); 4 waves x 16 q-rows. Computes S^T = K*Q^T so the
// score C-layout has qrow = lane&15 (softmax = 2 shuffles, P write = b64).
// K/V^T LDS tiles are chunk-XOR-swizzled to kill 16-way bank aliasing.
__global__ __launch_bounds__(256)
void attn_fwd(const u16* __restrict__ qh, const u16* __restrict__ kbh,
              const u16* __restrict__ vth, u16* __restrict__ ab) {
  __shared__ __align__(16) u16 lK[64 * 128];   // [kcol][d], swizzled
  __shared__ __align__(16) u16 lV[128 * 64];   // [d][kt],  swizzled (V^T)
  __shared__ __align__(16) u16 lP[4][16 * 72]; // per-wave P [qrow][kt], pad 72
  const int t = threadIdx.x, w = t >> 6, l = t & 63;
  const int quad = l >> 4, l15 = l & 15;
  const int h = blockIdx.x, qt = blockIdx.y;
  const int kvh = h >> 2;
  const int q0 = qt * 64;
  const int qrow = q0 + w * 16 + l15;

  bf16x8 qf[4];
#pragma unroll
  for (int ks = 0; ks < 4; ks++)
    qf[ks] = *(const bf16x8*)(qh + ((size_t)h * S_LEN + qrow) * HD + ks * 32 + quad * 8);

  f32x4 accO[8];
#pragma unroll
  for (int j = 0; j < 8; j++) accO[j] = (f32x4){0.f, 0.f, 0.f, 0.f};
  float m_cur = -3.0e38f, l_sum = 0.f;
  const float scale = 0.08838834764831845f;  // 1/sqrt(128)

  const int ntiles = qt + 1;
  for (int tt = 0; tt < ntiles; tt++) {
    const int c0 = tt * 64;
    // stage K tile (64x128, 16 chunks/row, chunk ch holds global chunk ch^(r&15))
#pragma unroll
    for (int i = 0; i < 4; i++) {
      int Cc = i * 256 + t;
      int r = Cc >> 4, ch = Cc & 15;
      int gch = ch ^ (r & 15);
      gld_lds16(kbh + ((size_t)kvh * S_LEN + c0 + r) * HD + gch * 8, lK + Cc * 8);
    }
    // stage V^T tile (128x64, 8 chunks/row, chunk ch holds global chunk ch^(d&7))
#pragma unroll
    for (int i = 0; i < 4; i++) {
      int Cc = i * 256 + t;
      int d = Cc >> 3, ch = Cc & 7;
      int gch = ch ^ (d & 7);
      gld_lds16(vth + ((size_t)kvh * HD + d) * S_LEN + c0 + gch * 8, lV + Cc * 8);
    }
    __syncthreads();

    // S^T tile: rows = kcols (4 mtiles), cols = 16 qrows of this wave
    f32x4 st[4];
#pragma unroll
    for (int i = 0; i < 4; i++) {
      f32x4 sa = (f32x4){0.f, 0.f, 0.f, 0.f};
      int r = i * 16 + l15;
#pragma unroll
      for (int ks = 0; ks < 4; ks++) {
        int lc = ks * 4 + quad;
        bf16x8 kf = *(const bf16x8*)(lK + r * 128 + ((lc ^ (r & 15)) * 8));
        sa = __builtin_amdgcn_mfma_f32_16x16x32_bf16(kf, qf[ks], sa, 0, 0, 0);
      }
      st[i] = sa;
    }

    // scale + causal mask + tile max (per lane: qrow = l15)
    float tmax = -3.0e38f;
#pragma unroll
    for (int i = 0; i < 4; i++) {
#pragma unroll
      for (int r = 0; r < 4; r++) {
        int kcol = c0 + i * 16 + quad * 4 + r;
        float v = st[i][r] * scale;
        v = (kcol <= qrow) ? v : -3.0e38f;
        st[i][r] = v;
        tmax = fmaxf(tmax, v);
      }
    }
    tmax = fmaxf(tmax, __shfl_xor(tmax, 16));
    tmax = fmaxf(tmax, __shfl_xor(tmax, 32));
    float m_new = fmaxf(m_cur, tmax);
    float alpha = __expf(m_cur - m_new);

    // P = exp(s - m_new), packed b64 writes (4 consecutive kt per lane)
    float psum = 0.f;
#pragma unroll
    for (int i = 0; i < 4; i++) {
      us4 pv;
      u16* pp = (u16*)&pv;
#pragma unroll
      for (int r = 0; r < 4; r++) {
        float pe = __expf(st[i][r] - m_new);
        psum += pe;
        pp[r] = f2bf(pe);
      }
      *(us4*)(&lP[w][l15 * 72 + i * 16 + quad * 4]) = pv;
    }
    psum += __shfl_xor(psum, 16);
    psum += __shfl_xor(psum, 32);
    l_sum = l_sum * alpha + psum;
    m_cur = m_new;

    // rescale O accumulator (alpha lives at lane (qrow&15); O rows = quad*4+r)
#pragma unroll
    for (int r = 0; r < 4; r++) {
      float ar = __shfl(alpha, quad * 4 + r);
#pragma unroll
      for (int j = 0; j < 8; j++) accO[j][r] *= ar;
    }

    // O += P * V
    bf16x8 pf[2];
#pragma unroll
    for (int ks = 0; ks < 2; ks++)
      pf[ks] = *(const bf16x8*)(&lP[w][l15 * 72 + ks * 32 + quad * 8]);
#pragma unroll
    for (int j = 0; j < 8; j++) {
      int d = j * 16 + l15;
#pragma unroll
      for (int ks = 0; ks < 2; ks++) {
        int lc = ks * 4 + quad;
        bf16x8 vf = *(const bf16x8*)(lV + d * 64 + ((lc ^ (d & 7)) * 8));
        accO[j] = __builtin_amdgcn_mfma_f32_16x16x32_bf16(pf[ks], vf, accO[j], 0, 0, 0);
      }
    }
    __syncthreads();
  }

  // epilogue: O[qrow][d] / l_sum -> ab[s][h*128+d] (bf16 row-major S x 4096)
  float linv = 1.0f / l_sum;
#pragma unroll
  for (int r = 0; r < 4; r++) {
    float lr = __shfl(linv, quad * 4 + r);
    int row = q0 + w * 16 + quad * 4 + r;
#pragma unroll
    for (int j = 0; j < 8; j++) {
      int col = h * HD + j * 16 + l15;
      ab[(size_t)row * HID + col] = f2bf(accO[j][r] * lr);
    }
  }
}

// ---------------- launch ----------------------------------------------------
extern "C" void kernel_launch(void* const* d_in, const int* in_sizes, int n_in,
                              void* d_out, int out_size, void* d_ws, size_t ws_size,
                              hipStream_t stream) {
  const float* x    = (const float*)d_in[0];
  const float* wq   = (const float*)d_in[1];
  const float* wk   = (const float*)d_in[2];
  const float* wv   = (const float*)d_in[3];
  const float* wo   = (const float*)d_in[4];
  const float* qnw  = (const float*)d_in[5];
  const float* knw  = (const float*)d_in[6];
  const float* cosT = (const float*)d_in[7];
  const float* sinT = (const float*)d_in[8];
  const int* positions = (const int*)d_in[11];

  char* ws = (char*)d_ws;
  u16* xb  = (u16*)(ws + 0ULL);          //  16 MB  x bf16 (2048x4096)
  u16* wqb = (u16*)(ws + 16777216ULL);   //  32 MB  wq bf16
  u16* wkb = (u16*)(ws + 50331648ULL);   //   8 MB  wk bf16
  u16* wvb = (u16*)(ws + 58720256ULL);   //   8 MB  wv bf16
  u16* wob = (u16*)(ws + 67108864ULL);   //  32 MB  wo bf16
  u16* Qp  = (u16*)(ws + 100663296ULL);  //  16 MB  q proj (S x 4096)
  u16* Kp  = (u16*)(ws + 117440512ULL);  //   4 MB  k proj (S x 1024)
  u16* vt  = (u16*)(ws + 121634816ULL);  //   4 MB  V^T (1024 x S)
  u16* qbh = (u16*)(ws + 125829120ULL);  //  16 MB  q heads (NH,S,D)
  u16* kbh = (u16*)(ws + 142606336ULL);  //   4 MB  k heads (KVH,S,D)
  u16* ab  = (u16*)(ws + 146800640ULL);  //  16 MB  attn out (S x 4096)
  // total 163,577,856 bytes

  cvt_bf16<<<8192, 256, 0, stream>>>(x, xb);
  cvt_bf16<<<16384, 256, 0, stream>>>(wq, wqb);
  cvt_bf16<<<4096, 256, 0, stream>>>(wk, wkb);
  cvt_bf16<<<4096, 256, 0, stream>>>(wv, wvb);
  cvt_bf16<<<16384, 256, 0, stream>>>(wo, wob);

  gemm_qkv<<<dim3(48, 16), 256, 0, stream>>>(xb, wqb, wkb, wvb, Qp, Kp, vt);

  rope_norm<NH><<<S_LEN * NH / 4, 256, 0, stream>>>(Qp, qnw, cosT, sinT, positions, qbh);
  rope_norm<KVH><<<S_LEN * KVH / 4, 256, 0, stream>>>(Kp, knw, cosT, sinT, positions, kbh);

  attn_fwd<<<dim3(NH, S_LEN / 64), 256, 0, stream>>>(qbh, kbh, vt, ab);

  gemm_out<<<dim3(HID / 128, S_LEN / 128), 256, 0, stream>>>(ab, wob, (float*)d_out);
}

// Round 2
// 592.593 us; speedup vs baseline: 1.0439x; 1.0439x over previous
//
#include <hip/hip_runtime.h>

typedef unsigned short u16;
typedef unsigned int u32;
typedef __attribute__((ext_vector_type(8))) short bf16x8;
typedef __attribute__((ext_vector_type(4))) float f32x4;
struct __align__(8) us4 { u16 x, y, z, w; };

#define S_LEN 2048
#define HID   4096
#define NH    32
#define KVH   8
#define HD    128

__device__ inline u16 f2bf(float f) {
  u32 u = __float_as_uint(f);
  u32 r = (u + 0x7fffu + ((u >> 16) & 1u)) >> 16;  // RNE
  return (u16)r;
}
__device__ inline float bf2f(u16 h) { return __uint_as_float(((u32)h) << 16); }

__device__ inline void gld_lds16(const void* g, void* l) {
  __builtin_amdgcn_global_load_lds(
      (const __attribute__((address_space(1))) u32*)g,
      (__attribute__((address_space(3))) u32*)l, 16, 0, 0);
}

// ---------------- fused fp32 -> bf16 conversion (all 5 tensors, 1 launch) ---
// block ranges: x 0..8191 | wq 8192..24575 | wk 24576..28671 | wv 28672..32767
//               wo 32768..49151
__global__ __launch_bounds__(256)
void cvt_all(const float* __restrict__ x, const float* __restrict__ wq,
             const float* __restrict__ wk, const float* __restrict__ wv,
             const float* __restrict__ wo, u16* __restrict__ xb,
             u16* __restrict__ wqb, u16* __restrict__ wkb,
             u16* __restrict__ wvb, u16* __restrict__ wob) {
  int b = blockIdx.x;
  const float* in; u16* out; int base;
  if (b < 8192)       { in = x;  out = xb;  base = b; }
  else if (b < 24576) { in = wq; out = wqb; base = b - 8192; }
  else if (b < 28672) { in = wk; out = wkb; base = b - 24576; }
  else if (b < 32768) { in = wv; out = wvb; base = b - 28672; }
  else                { in = wo; out = wob; base = b - 32768; }
  size_t i = ((size_t)base * 256 + threadIdx.x) * 4;
  f32x4 v = *(const f32x4*)(in + i);
  us4 o;
  o.x = f2bf(v[0]); o.y = f2bf(v[1]); o.z = f2bf(v[2]); o.w = f2bf(v[3]);
  *(us4*)(out + i) = o;
}

// ---------------- NT GEMM core: C(128x128) = A(MxK) * W(NxK)^T over k-range -
// m97 structure: BK=32, global_load_lds w16, 4 waves in 2x2, 4x4 16x16x32 MFMA
__device__ inline void gemm_core_128(const u16* __restrict__ A,
                                     const u16* __restrict__ W,
                                     int m0, int n0, int K,
                                     int kStart, int kEnd,
                                     u16* lA, u16* lB, f32x4 (&acc)[4][4]) {
  const int t = threadIdx.x;
  const int l = t & 63, w = t >> 6;
  const int quad = l >> 4, l15 = l & 15;
  const int wr = w >> 1, wc = w & 1;
  const int srow = t >> 2;          // 0..63
  const int scol = (t & 3) * 8;     // 0,8,16,24
#pragma unroll
  for (int i = 0; i < 4; i++)
#pragma unroll
    for (int j = 0; j < 4; j++) acc[i][j] = (f32x4){0.f, 0.f, 0.f, 0.f};

  for (int k0 = kStart; k0 < kEnd; k0 += 32) {
    gld_lds16(A + (size_t)(m0 + srow) * K + k0 + scol, lA + srow * 32 + scol);
    gld_lds16(A + (size_t)(m0 + 64 + srow) * K + k0 + scol, lA + (64 + srow) * 32 + scol);
    gld_lds16(W + (size_t)(n0 + srow) * K + k0 + scol, lB + srow * 32 + scol);
    gld_lds16(W + (size_t)(n0 + 64 + srow) * K + k0 + scol, lB + (64 + srow) * 32 + scol);
    __syncthreads();
    bf16x8 af[4], bfr[4];
#pragma unroll
    for (int i = 0; i < 4; i++)
      af[i] = *(const bf16x8*)(lA + (wr * 64 + i * 16 + l15) * 32 + quad * 8);
#pragma unroll
    for (int j = 0; j < 4; j++)
      bfr[j] = *(const bf16x8*)(lB + (wc * 64 + j * 16 + l15) * 32 + quad * 8);
#pragma unroll
    for (int i = 0; i < 4; i++)
#pragma unroll
      for (int j = 0; j < 4; j++)
        acc[i][j] = __builtin_amdgcn_mfma_f32_16x16x32_bf16(af[i], bfr[j], acc[i][j], 0, 0, 0);
    __syncthreads();
  }
}

// ---------------- fused QKV projection, split-K x2 --------------------------
// grid (48,16,2): x: 0..31 Q, 32..39 K, 40..47 V(transposed); z = K-slice.
// Partials written bf16; summed in rope_all.
#define QP_ELEMS (S_LEN * HID)
#define KP_ELEMS (S_LEN * 1024)
__global__ __launch_bounds__(256)
void gemm_qkv(const u16* __restrict__ xb, const u16* __restrict__ wqb,
              const u16* __restrict__ wkb, const u16* __restrict__ wvb,
              u16* __restrict__ Qp0, u16* __restrict__ Kp0, u16* __restrict__ vt0) {
  __shared__ __align__(16) u16 lA[128 * 32];
  __shared__ __align__(16) u16 lB[128 * 32];
  const int bx = blockIdx.x;
  const int m0 = blockIdx.y * 128;
  const int z = blockIdx.z;
  const u16* W; u16* C; int n0, ldc, epi;
  if (bx < 32)      { W = wqb; C = Qp0 + (size_t)z * QP_ELEMS; n0 = bx * 128;        ldc = HID;  epi = 0; }
  else if (bx < 40) { W = wkb; C = Kp0 + (size_t)z * KP_ELEMS; n0 = (bx - 32) * 128; ldc = 1024; epi = 0; }
  else              { W = wvb; C = vt0 + (size_t)z * KP_ELEMS; n0 = (bx - 40) * 128; ldc = 0;    epi = 1; }

  f32x4 acc[4][4];
  gemm_core_128(xb, W, m0, n0, HID, z * 2048, z * 2048 + 2048, lA, lB, acc);

  const int t = threadIdx.x, l = t & 63, w = t >> 6;
  const int quad = l >> 4, l15 = l & 15;
  const int wr = w >> 1, wc = w & 1;
  if (epi == 0) {
#pragma unroll
    for (int i = 0; i < 4; i++) {
      int row0 = m0 + wr * 64 + i * 16 + quad * 4;
#pragma unroll
      for (int j = 0; j < 4; j++) {
        int col = n0 + wc * 64 + j * 16 + l15;
#pragma unroll
        for (int r = 0; r < 4; r++)
          C[(size_t)(row0 + r) * ldc + col] = f2bf(acc[i][j][r]);
      }
    }
  } else {
#pragma unroll
    for (int i = 0; i < 4; i++) {
      int row0 = m0 + wr * 64 + i * 16 + quad * 4;
#pragma unroll
      for (int j = 0; j < 4; j++) {
        int col = n0 + wc * 64 + j * 16 + l15;
        us4 v;
        v.x = f2bf(acc[i][j][0]); v.y = f2bf(acc[i][j][1]);
        v.z = f2bf(acc[i][j][2]); v.w = f2bf(acc[i][j][3]);
        *(us4*)(C + (size_t)col * S_LEN + row0) = v;  // transposed store
      }
    }
  }
}

// ---------------- output projection split-K x2: Oz(f32) = ab * wo^T ---------
__global__ __launch_bounds__(256)
void gemm_out(const u16* __restrict__ ab, const u16* __restrict__ wob,
              float* __restrict__ O0, float* __restrict__ O1) {
  __shared__ __align__(16) u16 lA[128 * 32];
  __shared__ __align__(16) u16 lB[128 * 32];
  const int m0 = blockIdx.y * 128, n0 = blockIdx.x * 128;
  const int z = blockIdx.z;
  float* Op = z ? O1 : O0;
  f32x4 acc[4][4];
  gemm_core_128(ab, wob, m0, n0, HID, z * 2048, z * 2048 + 2048, lA, lB, acc);
  const int t = threadIdx.x, l = t & 63, w = t >> 6;
  const int quad = l >> 4, l15 = l & 15;
  const int wr = w >> 1, wc = w & 1;
#pragma unroll
  for (int i = 0; i < 4; i++) {
    int row0 = m0 + wr * 64 + i * 16 + quad * 4;
#pragma unroll
    for (int j = 0; j < 4; j++) {
      int col = n0 + wc * 64 + j * 16 + l15;
#pragma unroll
      for (int r = 0; r < 4; r++)
        Op[(size_t)(row0 + r) * HID + col] = acc[i][j][r];
    }
  }
}

__global__ __launch_bounds__(256)
void reduce_out(const float* __restrict__ O0, const float* __restrict__ O1,
                float* __restrict__ outp) {
  size_t i = ((size_t)blockIdx.x * 256 + threadIdx.x) * 4;
  f32x4 a = *(const f32x4*)(O0 + i);
  f32x4 b = *(const f32x4*)(O1 + i);
  a[0] += b[0]; a[1] += b[1]; a[2] += b[2]; a[3] += b[3];
  *(f32x4*)(outp + i) = a;
}

// ---------------- fused: partial-sum + RMSNorm + RoPE relayout + V-reduce ---
// blocks 0..16383: Q rope | 16384..20479: K rope | 20480..22527: vt reduce
__global__ __launch_bounds__(256)
void rope_all(const u16* __restrict__ Qp0, const u16* __restrict__ Kp0,
              const float* __restrict__ qnw, const float* __restrict__ knw,
              const float* __restrict__ cosT, const float* __restrict__ sinT,
              const int* __restrict__ pos, u16* __restrict__ qbh,
              u16* __restrict__ kbh, const u16* __restrict__ vt0,
              u16* __restrict__ vt) {
  const int b = blockIdx.x;
  const int t = threadIdx.x, w = t >> 6, l = t & 63;
  if (b >= 20480) {  // V partial reduce: vt = vt0 + vt1
    size_t i = ((size_t)(b - 20480) * 256 + t) * 4;
    us4 a = *(const us4*)(vt0 + i);
    us4 c = *(const us4*)(vt0 + KP_ELEMS + i);
    us4 o;
    o.x = f2bf(bf2f(a.x) + bf2f(c.x)); o.y = f2bf(bf2f(a.y) + bf2f(c.y));
    o.z = f2bf(bf2f(a.z) + bf2f(c.z)); o.w = f2bf(bf2f(a.w) + bf2f(c.w));
    *(us4*)(vt + i) = o;
    return;
  }
  const u16 *xr0, *xr1; const float* nw; u16* orow; int s;
  if (b < 16384) {       // Q: NH=32 heads
    int p = b * 4 + w;
    s = p >> 5; int h = p & 31;
    xr0 = Qp0 + (size_t)s * HID + h * HD;
    xr1 = xr0 + QP_ELEMS;
    nw = qnw;
    orow = qbh + ((size_t)h * S_LEN + s) * HD;
  } else {               // K: KVH=8 heads
    int p = (b - 16384) * 4 + w;
    s = p >> 3; int h = p & 7;
    xr0 = Kp0 + (size_t)s * 1024 + h * HD;
    xr1 = xr0 + KP_ELEMS;
    nw = knw;
    orow = kbh + ((size_t)h * S_LEN + s) * HD;
  }
  float x1 = bf2f(xr0[l]) + bf2f(xr1[l]);
  float x2 = bf2f(xr0[l + 64]) + bf2f(xr1[l + 64]);
  float ss = x1 * x1 + x2 * x2;
#pragma unroll
  for (int m = 1; m < 64; m <<= 1) ss += __shfl_xor(ss, m);
  float rinv = rsqrtf(ss * (1.0f / 128.0f) + 1e-6f);
  float n1 = x1 * rinv * nw[l];
  float n2 = x2 * rinv * nw[l + 64];
  int ps = pos[s];
  float c1 = cosT[ps * HD + l], s1 = sinT[ps * HD + l];
  float c2 = cosT[ps * HD + l + 64], s2 = sinT[ps * HD + l + 64];
  float y1 = n1 * c1 - n2 * s1;
  float y2 = n2 * c2 + n1 * s2;
  orow[l] = f2bf(y1);
  orow[l + 64] = f2bf(y2);
}

// ---------------- causal GQA flash attention --------------------------------
__global__ __launch_bounds__(256)
void attn_fwd(const u16* __restrict__ qh, const u16* __restrict__ kbh,
              const u16* __restrict__ vth, u16* __restrict__ ab) {
  __shared__ __align__(16) u16 lK[64 * 128];
  __shared__ __align__(16) u16 lV[128 * 64];
  __shared__ __align__(16) u16 lP[4][16 * 72];
  const int t = threadIdx.x, w = t >> 6, l = t & 63;
  const int quad = l >> 4, l15 = l & 15;
  const int h = blockIdx.x;
  const int qt = 31 - blockIdx.y;   // heavy blocks first
  const int kvh = h >> 2;
  const int q0 = qt * 64;
  const int qrow = q0 + w * 16 + l15;

  bf16x8 qf[4];
#pragma unroll
  for (int ks = 0; ks < 4; ks++)
    qf[ks] = *(const bf16x8*)(qh + ((size_t)h * S_LEN + qrow) * HD + ks * 32 + quad * 8);

  f32x4 accO[8];
#pragma unroll
  for (int j = 0; j < 8; j++) accO[j] = (f32x4){0.f, 0.f, 0.f, 0.f};
  float m_cur = -3.0e38f, l_sum = 0.f;
  const float scale = 0.08838834764831845f;

  const int ntiles = qt + 1;
  for (int tt = 0; tt < ntiles; tt++) {
    const int c0 = tt * 64;
#pragma unroll
    for (int i = 0; i < 4; i++) {
      int Cc = i * 256 + t;
      int r = Cc >> 4, ch = Cc & 15;
      int gch = ch ^ (r & 15);
      gld_lds16(kbh + ((size_t)kvh * S_LEN + c0 + r) * HD + gch * 8, lK + Cc * 8);
    }
#pragma unroll
    for (int i = 0; i < 4; i++) {
      int Cc = i * 256 + t;
      int d = Cc >> 3, ch = Cc & 7;
      int gch = ch ^ (d & 7);
      gld_lds16(vth + ((size_t)kvh * HD + d) * S_LEN + c0 + gch * 8, lV + Cc * 8);
    }
    __syncthreads();

    f32x4 st[4];
#pragma unroll
    for (int i = 0; i < 4; i++) {
      f32x4 sa = (f32x4){0.f, 0.f, 0.f, 0.f};
      int r = i * 16 + l15;
#pragma unroll
      for (int ks = 0; ks < 4; ks++) {
        int lc = ks * 4 + quad;
        bf16x8 kf = *(const bf16x8*)(lK + r * 128 + ((lc ^ (r & 15)) * 8));
        sa = __builtin_amdgcn_mfma_f32_16x16x32_bf16(kf, qf[ks], sa, 0, 0, 0);
      }
      st[i] = sa;
    }

    float tmax = -3.0e38f;
#pragma unroll
    for (int i = 0; i < 4; i++) {
#pragma unroll
      for (int r = 0; r < 4; r++) {
        int kcol = c0 + i * 16 + quad * 4 + r;
        float v = st[i][r] * scale;
        v = (kcol <= qrow) ? v : -3.0e38f;
        st[i][r] = v;
        tmax = fmaxf(tmax, v);
      }
    }
    tmax = fmaxf(tmax, __shfl_xor(tmax, 16));
    tmax = fmaxf(tmax, __shfl_xor(tmax, 32));
    float m_new = fmaxf(m_cur, tmax);
    float alpha = __expf(m_cur - m_new);

    float psum = 0.f;
#pragma unroll
    for (int i = 0; i < 4; i++) {
      us4 pv;
      u16* pp = (u16*)&pv;
#pragma unroll
      for (int r = 0; r < 4; r++) {
        float pe = __expf(st[i][r] - m_new);
        psum += pe;
        pp[r] = f2bf(pe);
      }
      *(us4*)(&lP[w][l15 * 72 + i * 16 + quad * 4]) = pv;
    }
    psum += __shfl_xor(psum, 16);
    psum += __shfl_xor(psum, 32);
    l_sum = l_sum * alpha + psum;
    m_cur = m_new;

#pragma unroll
    for (int r = 0; r < 4; r++) {
      float ar = __shfl(alpha, quad * 4 + r);
#pragma unroll
      for (int j = 0; j < 8; j++) accO[j][r] *= ar;
    }

    bf16x8 pf[2];
#pragma unroll
    for (int ks = 0; ks < 2; ks++)
      pf[ks] = *(const bf16x8*)(&lP[w][l15 * 72 + ks * 32 + quad * 8]);
#pragma unroll
    for (int j = 0; j < 8; j++) {
      int d = j * 16 + l15;
#pragma unroll
      for (int ks = 0; ks < 2; ks++) {
        int lc = ks * 4 + quad;
        bf16x8 vf = *(const bf16x8*)(lV + d * 64 + ((lc ^ (d & 7)) * 8));
        accO[j] = __builtin_amdgcn_mfma_f32_16x16x32_bf16(pf[ks], vf, accO[j], 0, 0, 0);
      }
    }
    __syncthreads();
  }

  float linv = 1.0f / l_sum;
#pragma unroll
  for (int r = 0; r < 4; r++) {
    float lr = __shfl(linv, quad * 4 + r);
    int row = q0 + w * 16 + quad * 4 + r;
#pragma unroll
    for (int j = 0; j < 8; j++) {
      int col = h * HD + j * 16 + l15;
      ab[(size_t)row * HID + col] = f2bf(accO[j][r] * lr);
    }
  }
}

// ---------------- launch ----------------------------------------------------
extern "C" void kernel_launch(void* const* d_in, const int* in_sizes, int n_in,
                              void* d_out, int out_size, void* d_ws, size_t ws_size,
                              hipStream_t stream) {
  const float* x    = (const float*)d_in[0];
  const float* wq   = (const float*)d_in[1];
  const float* wk   = (const float*)d_in[2];
  const float* wv   = (const float*)d_in[3];
  const float* wo   = (const float*)d_in[4];
  const float* qnw  = (const float*)d_in[5];
  const float* knw  = (const float*)d_in[6];
  const float* cosT = (const float*)d_in[7];
  const float* sinT = (const float*)d_in[8];
  const int* positions = (const int*)d_in[11];

  char* ws = (char*)d_ws;
  u16* xb  = (u16*)(ws + 0ULL);          //  16 MB  x bf16
  u16* wqb = (u16*)(ws + 16777216ULL);   //  32 MB  wq bf16
  u16* wkb = (u16*)(ws + 50331648ULL);   //   8 MB  wk bf16
  u16* wvb = (u16*)(ws + 58720256ULL);   //   8 MB  wv bf16
  u16* wob = (u16*)(ws + 67108864ULL);   //  32 MB  wo bf16
  u16* Qp0 = (u16*)(ws + 100663296ULL);  //  16+16 MB q partials (z=0,1)
  u16* Kp0 = (u16*)(ws + 134217728ULL);  //   4+4 MB  k partials
  u16* vt0 = (u16*)(ws + 142606336ULL);  //   4+4 MB  V^T partials
  u16* vt  = (u16*)(ws + 150994944ULL);  //   4 MB  V^T reduced
  u16* qbh = (u16*)(ws + 155189248ULL);  //  16 MB  q heads (NH,S,D)
  u16* kbh = (u16*)(ws + 171966464ULL);  //   4 MB  k heads (KVH,S,D)
  u16* ab  = (u16*)(ws + 176160768ULL);  //  16 MB  attn out (S x 4096)
  // aliases (dead buffers): O0 over wqb (dead after gemm_qkv),
  // O1 over Qp0/Qp1 (dead after rope_all)
  float* O0 = (float*)(ws + 16777216ULL);   // 32 MB fp32
  float* O1 = (float*)(ws + 100663296ULL);  // 32 MB fp32
  // high-water mark: 192 MB

  cvt_all<<<49152, 256, 0, stream>>>(x, wq, wk, wv, wo, xb, wqb, wkb, wvb, wob);

  gemm_qkv<<<dim3(48, 16, 2), 256, 0, stream>>>(xb, wqb, wkb, wvb, Qp0, Kp0, vt0);

  rope_all<<<22528, 256, 0, stream>>>(Qp0, Kp0, qnw, knw, cosT, sinT, positions,
                                      qbh, kbh, vt0, vt);

  attn_fwd<<<dim3(NH, S_LEN / 64), 256, 0, stream>>>(qbh, kbh, vt, ab);

  gemm_out<<<dim3(HID / 128, S_LEN / 128, 2), 256, 0, stream>>>(ab, wob, O0, O1);
  reduce_out<<<8192, 256, 0, stream>>>(O0, O1, (float*)d_out);
}

// Round 3
// 541.236 us; speedup vs baseline: 1.1430x; 1.0949x over previous
//
#include <hip/hip_runtime.h>

typedef unsigned short u16;
typedef unsigned int u32;
typedef __attribute__((ext_vector_type(8))) short bf16x8;
typedef __attribute__((ext_vector_type(4))) float f32x4;
struct __align__(8) us4 { u16 x, y, z, w; };

#define S_LEN 2048
#define HID   4096
#define NH    32
#define KVH   8
#define HD    128

__device__ inline u16 f2bf(float f) {
  u32 u = __float_as_uint(f);
  u32 r = (u + 0x7fffu + ((u >> 16) & 1u)) >> 16;  // RNE
  return (u16)r;
}
__device__ inline float bf2f(u16 h) { return __uint_as_float(((u32)h) << 16); }

__device__ inline void gld_lds16(const void* g, void* l) {
  __builtin_amdgcn_global_load_lds(
      (const __attribute__((address_space(1))) u32*)g,
      (__attribute__((address_space(3))) u32*)l, 16, 0, 0);
}

// ---------------- fused fp32 -> bf16 conversion (all 5 tensors, 1 launch) ---
__global__ __launch_bounds__(256)
void cvt_all(const float* __restrict__ x, const float* __restrict__ wq,
             const float* __restrict__ wk, const float* __restrict__ wv,
             const float* __restrict__ wo, u16* __restrict__ xb,
             u16* __restrict__ wqb, u16* __restrict__ wkb,
             u16* __restrict__ wvb, u16* __restrict__ wob) {
  int b = blockIdx.x;
  const float* in; u16* out; int base;
  if (b < 8192)       { in = x;  out = xb;  base = b; }
  else if (b < 24576) { in = wq; out = wqb; base = b - 8192; }
  else if (b < 28672) { in = wk; out = wkb; base = b - 24576; }
  else if (b < 32768) { in = wv; out = wvb; base = b - 28672; }
  else                { in = wo; out = wob; base = b - 32768; }
  size_t i = ((size_t)base * 256 + threadIdx.x) * 4;
  f32x4 v = *(const f32x4*)(in + i);
  us4 o;
  o.x = f2bf(v[0]); o.y = f2bf(v[1]); o.z = f2bf(v[2]); o.w = f2bf(v[3]);
  *(us4*)(out + i) = o;
}

// ---------------- NT GEMM core: C(128x128) = A(MxK) * W(NxK)^T over k-range -
__device__ inline void gemm_core_128(const u16* __restrict__ A,
                                     const u16* __restrict__ W,
                                     int m0, int n0, int K,
                                     int kStart, int kEnd,
                                     u16* lA, u16* lB, f32x4 (&acc)[4][4]) {
  const int t = threadIdx.x;
  const int l = t & 63, w = t >> 6;
  const int quad = l >> 4, l15 = l & 15;
  const int wr = w >> 1, wc = w & 1;
  const int srow = t >> 2;          // 0..63
  const int scol = (t & 3) * 8;     // 0,8,16,24
#pragma unroll
  for (int i = 0; i < 4; i++)
#pragma unroll
    for (int j = 0; j < 4; j++) acc[i][j] = (f32x4){0.f, 0.f, 0.f, 0.f};

  for (int k0 = kStart; k0 < kEnd; k0 += 32) {
    gld_lds16(A + (size_t)(m0 + srow) * K + k0 + scol, lA + srow * 32 + scol);
    gld_lds16(A + (size_t)(m0 + 64 + srow) * K + k0 + scol, lA + (64 + srow) * 32 + scol);
    gld_lds16(W + (size_t)(n0 + srow) * K + k0 + scol, lB + srow * 32 + scol);
    gld_lds16(W + (size_t)(n0 + 64 + srow) * K + k0 + scol, lB + (64 + srow) * 32 + scol);
    __syncthreads();
    bf16x8 af[4], bfr[4];
#pragma unroll
    for (int i = 0; i < 4; i++)
      af[i] = *(const bf16x8*)(lA + (wr * 64 + i * 16 + l15) * 32 + quad * 8);
#pragma unroll
    for (int j = 0; j < 4; j++)
      bfr[j] = *(const bf16x8*)(lB + (wc * 64 + j * 16 + l15) * 32 + quad * 8);
#pragma unroll
    for (int i = 0; i < 4; i++)
#pragma unroll
      for (int j = 0; j < 4; j++)
        acc[i][j] = __builtin_amdgcn_mfma_f32_16x16x32_bf16(af[i], bfr[j], acc[i][j], 0, 0, 0);
    __syncthreads();
  }
}

// ---------------- fused QKV projection, split-K x2 --------------------------
#define QP_ELEMS (S_LEN * HID)
#define KP_ELEMS (S_LEN * 1024)
// __launch_bounds__(256,3): combined VGPR+AGPR was 108+64=172, 4 regs over the
// 3-waves/SIMD cutoff (~168) -> only 2 blocks/CU resident (Occ 21%). Force 3.
__global__ __launch_bounds__(256, 3)
void gemm_qkv(const u16* __restrict__ xb, const u16* __restrict__ wqb,
              const u16* __restrict__ wkb, const u16* __restrict__ wvb,
              u16* __restrict__ Qp0, u16* __restrict__ Kp0, u16* __restrict__ vt0) {
  __shared__ __align__(16) u16 lA[128 * 32];
  __shared__ __align__(16) u16 lB[128 * 32];
  const int bx = blockIdx.x;
  const int m0 = blockIdx.y * 128;
  const int z = blockIdx.z;
  const u16* W; u16* C; int n0, ldc, epi;
  if (bx < 32)      { W = wqb; C = Qp0 + (size_t)z * QP_ELEMS; n0 = bx * 128;        ldc = HID;  epi = 0; }
  else if (bx < 40) { W = wkb; C = Kp0 + (size_t)z * KP_ELEMS; n0 = (bx - 32) * 128; ldc = 1024; epi = 0; }
  else              { W = wvb; C = vt0 + (size_t)z * KP_ELEMS; n0 = (bx - 40) * 128; ldc = 0;    epi = 1; }

  f32x4 acc[4][4];
  gemm_core_128(xb, W, m0, n0, HID, z * 2048, z * 2048 + 2048, lA, lB, acc);

  const int t = threadIdx.x, l = t & 63, w = t >> 6;
  const int quad = l >> 4, l15 = l & 15;
  const int wr = w >> 1, wc = w & 1;
  if (epi == 0) {
#pragma unroll
    for (int i = 0; i < 4; i++) {
      int row0 = m0 + wr * 64 + i * 16 + quad * 4;
#pragma unroll
      for (int j = 0; j < 4; j++) {
        int col = n0 + wc * 64 + j * 16 + l15;
#pragma unroll
        for (int r = 0; r < 4; r++)
          C[(size_t)(row0 + r) * ldc + col] = f2bf(acc[i][j][r]);
      }
    }
  } else {
#pragma unroll
    for (int i = 0; i < 4; i++) {
      int row0 = m0 + wr * 64 + i * 16 + quad * 4;
#pragma unroll
      for (int j = 0; j < 4; j++) {
        int col = n0 + wc * 64 + j * 16 + l15;
        us4 v;
        v.x = f2bf(acc[i][j][0]); v.y = f2bf(acc[i][j][1]);
        v.z = f2bf(acc[i][j][2]); v.w = f2bf(acc[i][j][3]);
        *(us4*)(C + (size_t)col * S_LEN + row0) = v;  // transposed store
      }
    }
  }
}

// ---------------- output projection split-K x2: Oz(f32) = ab * wo^T ---------
__global__ __launch_bounds__(256, 3)
void gemm_out(const u16* __restrict__ ab, const u16* __restrict__ wob,
              float* __restrict__ O0, float* __restrict__ O1) {
  __shared__ __align__(16) u16 lA[128 * 32];
  __shared__ __align__(16) u16 lB[128 * 32];
  const int m0 = blockIdx.y * 128, n0 = blockIdx.x * 128;
  const int z = blockIdx.z;
  float* Op = z ? O1 : O0;
  f32x4 acc[4][4];
  gemm_core_128(ab, wob, m0, n0, HID, z * 2048, z * 2048 + 2048, lA, lB, acc);
  const int t = threadIdx.x, l = t & 63, w = t >> 6;
  const int quad = l >> 4, l15 = l & 15;
  const int wr = w >> 1, wc = w & 1;
#pragma unroll
  for (int i = 0; i < 4; i++) {
    int row0 = m0 + wr * 64 + i * 16 + quad * 4;
#pragma unroll
    for (int j = 0; j < 4; j++) {
      int col = n0 + wc * 64 + j * 16 + l15;
#pragma unroll
      for (int r = 0; r < 4; r++)
        Op[(size_t)(row0 + r) * HID + col] = acc[i][j][r];
    }
  }
}

__global__ __launch_bounds__(256)
void reduce_out(const float* __restrict__ O0, const float* __restrict__ O1,
                float* __restrict__ outp) {
  size_t i = ((size_t)blockIdx.x * 256 + threadIdx.x) * 4;
  f32x4 a = *(const f32x4*)(O0 + i);
  f32x4 b = *(const f32x4*)(O1 + i);
  a[0] += b[0]; a[1] += b[1]; a[2] += b[2]; a[3] += b[3];
  *(f32x4*)(outp + i) = a;
}

// ---------------- fused: partial-sum + RMSNorm + RoPE relayout + V-reduce ---
__global__ __launch_bounds__(256)
void rope_all(const u16* __restrict__ Qp0, const u16* __restrict__ Kp0,
              const float* __restrict__ qnw, const float* __restrict__ knw,
              const float* __restrict__ cosT, const float* __restrict__ sinT,
              const int* __restrict__ pos, u16* __restrict__ qbh,
              u16* __restrict__ kbh, const u16* __restrict__ vt0,
              u16* __restrict__ vt) {
  const int b = blockIdx.x;
  const int t = threadIdx.x, w = t >> 6, l = t & 63;
  if (b >= 20480) {  // V partial reduce: vt = vt0 + vt1
    size_t i = ((size_t)(b - 20480) * 256 + t) * 4;
    us4 a = *(const us4*)(vt0 + i);
    us4 c = *(const us4*)(vt0 + KP_ELEMS + i);
    us4 o;
    o.x = f2bf(bf2f(a.x) + bf2f(c.x)); o.y = f2bf(bf2f(a.y) + bf2f(c.y));
    o.z = f2bf(bf2f(a.z) + bf2f(c.z)); o.w = f2bf(bf2f(a.w) + bf2f(c.w));
    *(us4*)(vt + i) = o;
    return;
  }
  const u16 *xr0, *xr1; const float* nw; u16* orow; int s;
  if (b < 16384) {       // Q: NH=32 heads
    int p = b * 4 + w;
    s = p >> 5; int h = p & 31;
    xr0 = Qp0 + (size_t)s * HID + h * HD;
    xr1 = xr0 + QP_ELEMS;
    nw = qnw;
    orow = qbh + ((size_t)h * S_LEN + s) * HD;
  } else {               // K: KVH=8 heads
    int p = (b - 16384) * 4 + w;
    s = p >> 3; int h = p & 7;
    xr0 = Kp0 + (size_t)s * 1024 + h * HD;
    xr1 = xr0 + KP_ELEMS;
    nw = knw;
    orow = kbh + ((size_t)h * S_LEN + s) * HD;
  }
  float x1 = bf2f(xr0[l]) + bf2f(xr1[l]);
  float x2 = bf2f(xr0[l + 64]) + bf2f(xr1[l + 64]);
  float ss = x1 * x1 + x2 * x2;
#pragma unroll
  for (int m = 1; m < 64; m <<= 1) ss += __shfl_xor(ss, m);
  float rinv = rsqrtf(ss * (1.0f / 128.0f) + 1e-6f);
  float n1 = x1 * rinv * nw[l];
  float n2 = x2 * rinv * nw[l + 64];
  int ps = pos[s];
  float c1 = cosT[ps * HD + l], s1 = sinT[ps * HD + l];
  float c2 = cosT[ps * HD + l + 64], s2 = sinT[ps * HD + l + 64];
  float y1 = n1 * c1 - n2 * s1;
  float y2 = n2 * c2 + n1 * s2;
  orow[l] = f2bf(y1);
  orow[l + 64] = f2bf(y2);
}

// ---------------- causal GQA flash attention --------------------------------
__global__ __launch_bounds__(256)
void attn_fwd(const u16* __restrict__ qh, const u16* __restrict__ kbh,
              const u16* __restrict__ vth, u16* __restrict__ ab) {
  __shared__ __align__(16) u16 lK[64 * 128];
  __shared__ __align__(16) u16 lV[128 * 64];
  __shared__ __align__(16) u16 lP[4][16 * 72];
  const int t = threadIdx.x, w = t >> 6, l = t & 63;
  const int quad = l >> 4, l15 = l & 15;
  const int h = blockIdx.x;
  const int qt = 31 - blockIdx.y;   // heavy blocks first
  const int kvh = h >> 2;
  const int q0 = qt * 64;
  const int qrow = q0 + w * 16 + l15;

  bf16x8 qf[4];
#pragma unroll
  for (int ks = 0; ks < 4; ks++)
    qf[ks] = *(const bf16x8*)(qh + ((size_t)h * S_LEN + qrow) * HD + ks * 32 + quad * 8);

  f32x4 accO[8];
#pragma unroll
  for (int j = 0; j < 8; j++) accO[j] = (f32x4){0.f, 0.f, 0.f, 0.f};
  float m_cur = -3.0e38f, l_sum = 0.f;
  const float scale = 0.08838834764831845f;

  const int ntiles = qt + 1;
  for (int tt = 0; tt < ntiles; tt++) {
    const int c0 = tt * 64;
#pragma unroll
    for (int i = 0; i < 4; i++) {
      int Cc = i * 256 + t;
      int r = Cc >> 4, ch = Cc & 15;
      int gch = ch ^ (r & 15);
      gld_lds16(kbh + ((size_t)kvh * S_LEN + c0 + r) * HD + gch * 8, lK + Cc * 8);
    }
#pragma unroll
    for (int i = 0; i < 4; i++) {
      int Cc = i * 256 + t;
      int d = Cc >> 3, ch = Cc & 7;
      int gch = ch ^ (d & 7);
      gld_lds16(vth + ((size_t)kvh * HD + d) * S_LEN + c0 + gch * 8, lV + Cc * 8);
    }
    __syncthreads();

    f32x4 st[4];
#pragma unroll
    for (int i = 0; i < 4; i++) {
      f32x4 sa = (f32x4){0.f, 0.f, 0.f, 0.f};
      int r = i * 16 + l15;
#pragma unroll
      for (int ks = 0; ks < 4; ks++) {
        int lc = ks * 4 + quad;
        bf16x8 kf = *(const bf16x8*)(lK + r * 128 + ((lc ^ (r & 15)) * 8));
        sa = __builtin_amdgcn_mfma_f32_16x16x32_bf16(kf, qf[ks], sa, 0, 0, 0);
      }
      st[i] = sa;
    }

    float tmax = -3.0e38f;
#pragma unroll
    for (int i = 0; i < 4; i++) {
#pragma unroll
      for (int r = 0; r < 4; r++) {
        int kcol = c0 + i * 16 + quad * 4 + r;
        float v = st[i][r] * scale;
        v = (kcol <= qrow) ? v : -3.0e38f;
        st[i][r] = v;
        tmax = fmaxf(tmax, v);
      }
    }
    tmax = fmaxf(tmax, __shfl_xor(tmax, 16));
    tmax = fmaxf(tmax, __shfl_xor(tmax, 32));
    float m_new = fmaxf(m_cur, tmax);
    float alpha = __expf(m_cur - m_new);

    float psum = 0.f;
#pragma unroll
    for (int i = 0; i < 4; i++) {
      us4 pv;
      u16* pp = (u16*)&pv;
#pragma unroll
      for (int r = 0; r < 4; r++) {
        float pe = __expf(st[i][r] - m_new);
        psum += pe;
        pp[r] = f2bf(pe);
      }
      *(us4*)(&lP[w][l15 * 72 + i * 16 + quad * 4]) = pv;
    }
    psum += __shfl_xor(psum, 16);
    psum += __shfl_xor(psum, 32);
    l_sum = l_sum * alpha + psum;
    m_cur = m_new;

#pragma unroll
    for (int r = 0; r < 4; r++) {
      float ar = __shfl(alpha, quad * 4 + r);
#pragma unroll
      for (int j = 0; j < 8; j++) accO[j][r] *= ar;
    }

    bf16x8 pf[2];
#pragma unroll
    for (int ks = 0; ks < 2; ks++)
      pf[ks] = *(const bf16x8*)(&lP[w][l15 * 72 + ks * 32 + quad * 8]);
#pragma unroll
    for (int j = 0; j < 8; j++) {
      int d = j * 16 + l15;
#pragma unroll
      for (int ks = 0; ks < 2; ks++) {
        int lc = ks * 4 + quad;
        bf16x8 vf = *(const bf16x8*)(lV + d * 64 + ((lc ^ (d & 7)) * 8));
        accO[j] = __builtin_amdgcn_mfma_f32_16x16x32_bf16(pf[ks], vf, accO[j], 0, 0, 0);
      }
    }
    __syncthreads();
  }

  float linv = 1.0f / l_sum;
#pragma unroll
  for (int r = 0; r < 4; r++) {
    float lr = __shfl(linv, quad * 4 + r);
    int row = q0 + w * 16 + quad * 4 + r;
#pragma unroll
    for (int j = 0; j < 8; j++) {
      int col = h * HD + j * 16 + l15;
      ab[(size_t)row * HID + col] = f2bf(accO[j][r] * lr);
    }
  }
}

// ---------------- launch ----------------------------------------------------
extern "C" void kernel_launch(void* const* d_in, const int* in_sizes, int n_in,
                              void* d_out, int out_size, void* d_ws, size_t ws_size,
                              hipStream_t stream) {
  const float* x    = (const float*)d_in[0];
  const float* wq   = (const float*)d_in[1];
  const float* wk   = (const float*)d_in[2];
  const float* wv   = (const float*)d_in[3];
  const float* wo   = (const float*)d_in[4];
  const float* qnw  = (const float*)d_in[5];
  const float* knw  = (const float*)d_in[6];
  const float* cosT = (const float*)d_in[7];
  const float* sinT = (const float*)d_in[8];
  const int* positions = (const int*)d_in[11];

  char* ws = (char*)d_ws;
  u16* xb  = (u16*)(ws + 0ULL);          //  16 MB  x bf16
  u16* wqb = (u16*)(ws + 16777216ULL);   //  32 MB  wq bf16
  u16* wkb = (u16*)(ws + 50331648ULL);   //   8 MB  wk bf16
  u16* wvb = (u16*)(ws + 58720256ULL);   //   8 MB  wv bf16
  u16* wob = (u16*)(ws + 67108864ULL);   //  32 MB  wo bf16
  u16* Qp0 = (u16*)(ws + 100663296ULL);  //  16+16 MB q partials (z=0,1)
  u16* Kp0 = (u16*)(ws + 134217728ULL);  //   4+4 MB  k partials
  u16* vt0 = (u16*)(ws + 142606336ULL);  //   4+4 MB  V^T partials
  u16* vt  = (u16*)(ws + 150994944ULL);  //   4 MB  V^T reduced
  u16* qbh = (u16*)(ws + 155189248ULL);  //  16 MB  q heads (NH,S,D)
  u16* kbh = (u16*)(ws + 171966464ULL);  //   4 MB  k heads (KVH,S,D)
  u16* ab  = (u16*)(ws + 176160768ULL);  //  16 MB  attn out (S x 4096)
  float* O0 = (float*)(ws + 16777216ULL);   // 32 MB fp32 (aliases wqb, dead)
  float* O1 = (float*)(ws + 100663296ULL);  // 32 MB fp32 (aliases Qp0, dead)

  cvt_all<<<49152, 256, 0, stream>>>(x, wq, wk, wv, wo, xb, wqb, wkb, wvb, wob);

  gemm_qkv<<<dim3(48, 16, 2), 256, 0, stream>>>(xb, wqb, wkb, wvb, Qp0, Kp0, vt0);

  rope_all<<<22528, 256, 0, stream>>>(Qp0, Kp0, qnw, knw, cosT, sinT, positions,
                                      qbh, kbh, vt0, vt);

  attn_fwd<<<dim3(NH, S_LEN / 64), 256, 0, stream>>>(qbh, kbh, vt, ab);

  gemm_out<<<dim3(HID / 128, S_LEN / 128, 2), 256, 0, stream>>>(ab, wob, O0, O1);
  reduce_out<<<8192, 256, 0, stream>>>(O0, O1, (float*)d_out);
}